// Round 1
// baseline (209.343 us; speedup 1.0000x reference)
//
#include <hip/hip_runtime.h>
#include <hip/hip_bf16.h>

// Shapes (fixed by the reference):
//   edges     [E=4096, 2]        int32
//   neigh_idx [N=100000, K=10]   int32
//   features  [N, 256]           f32
//   W1        [128, 256]         f32
//   W2        [128, 128]         f32
//   Wc        [2, 128]           f32
// out = [E, 2] f32
//
// Restructure (all linear ops commute with the neighbor means):
//   z  = features @ W1^T                       (dense GEMM, bf16 MFMA, z stored bf16)
//   h1m[e,p] = mean_k relu( mean_j z[neigh[neigh[edges[e,p]][k]][j]] )
//   out[e]   = (0.5*(h1m[e,0]+h1m[e,1])) @ (Wc@W2)^T

typedef __bf16 bf16x8 __attribute__((ext_vector_type(8)));
typedef float f32x4 __attribute__((ext_vector_type(4)));

#define FEAT 256
#define EMB  128
#define KNB  10

__device__ inline unsigned short f2b(float f) {
  unsigned int u = __float_as_uint(f);
  unsigned int r = (u + 0x7fffu + ((u >> 16) & 1u)) >> 16;  // RNE
  return (unsigned short)r;
}
__device__ inline float b2f(unsigned short s) {
  return __uint_as_float(((unsigned int)s) << 16);
}

// ---- tiny setup kernels -------------------------------------------------

__global__ void cvt_w1(const float* __restrict__ W1, unsigned short* __restrict__ w1b) {
  int i = blockIdx.x * 256 + threadIdx.x;
  if (i < EMB * FEAT) w1b[i] = f2b(W1[i]);
}

// M2 = Wc @ W2  -> [2,128] f32
__global__ void make_m2(const float* __restrict__ W2, const float* __restrict__ Wc,
                        float* __restrict__ M2) {
  int t = threadIdx.x;          // 256 threads: c = t>>7, d = t&127
  int c = t >> 7, d = t & 127;
  float s = 0.f;
  for (int g = 0; g < EMB; ++g) s += Wc[c * EMB + g] * W2[g * EMB + d];
  M2[t] = s;
}

// ---- z = features @ W1^T  (bf16 MFMA, f32 accum, bf16 out) --------------
// block = 512 threads (8 waves). Each wave owns one 16-col n-tile, block does
// a 64-row M chunk. W1 fragments live in VGPRs; A tile staged f32->bf16 in LDS.

__global__ __launch_bounds__(512, 4) void gemm_z(
    const float* __restrict__ feat, const unsigned short* __restrict__ w1b,
    unsigned short* __restrict__ z, int M) {
  __shared__ unsigned short As[64][FEAT + 8];   // +8 bf16 pad: conflict-free b128 reads

  const int wid  = threadIdx.x >> 6;   // 0..7  -> n-tile
  const int lane = threadIdx.x & 63;
  const int m0   = blockIdx.x * 64;

  // B fragments: B[k][col] = W1[col][k]; lane holds col=(lane&15), k=kk*32+(lane>>4)*8+i
  bf16x8 bfrag[8];
  {
    const int col = wid * 16 + (lane & 15);
    const int kof = (lane >> 4) * 8;
#pragma unroll
    for (int kk = 0; kk < 8; ++kk)
      bfrag[kk] = *reinterpret_cast<const bf16x8*>(&w1b[col * FEAT + kk * 32 + kof]);
  }

  // stage A tile: 64 rows x 256 f32 -> bf16 LDS (zero-pad tail rows)
  const float4* f4 = reinterpret_cast<const float4*>(feat);
  for (int i = threadIdx.x; i < 64 * 64; i += 512) {
    int r = i >> 6, c4 = i & 63;
    int row = m0 + r;
    float4 v = make_float4(0.f, 0.f, 0.f, 0.f);
    if (row < M) v = f4[(size_t)row * 64 + c4];
    ushort4 b;
    b.x = f2b(v.x); b.y = f2b(v.y); b.z = f2b(v.z); b.w = f2b(v.w);
    *reinterpret_cast<ushort4*>(&As[r][c4 * 4]) = b;
  }
  __syncthreads();

  f32x4 acc[4] = {};
  const int arow = lane & 15;
  const int kof  = (lane >> 4) * 8;
#pragma unroll
  for (int mt = 0; mt < 4; ++mt) {
#pragma unroll
    for (int kk = 0; kk < 8; ++kk) {
      bf16x8 a = *reinterpret_cast<const bf16x8*>(&As[mt * 16 + arow][kk * 32 + kof]);
      acc[mt] = __builtin_amdgcn_mfma_f32_16x16x32_bf16(a, bfrag[kk], acc[mt], 0, 0, 0);
    }
  }

  // D layout: col = lane&15, row = (lane>>4)*4 + reg
  const int col = wid * 16 + (lane & 15);
#pragma unroll
  for (int mt = 0; mt < 4; ++mt) {
    int rbase = m0 + mt * 16 + (lane >> 4) * 4;
#pragma unroll
    for (int r = 0; r < 4; ++r) {
      int row = rbase + r;
      if (row < M) z[(size_t)row * EMB + col] = f2b(acc[mt][r]);
    }
  }
}

// ---- per-edge aggregation + classifier ----------------------------------
// one block (128 threads = 2 waves) per edge; thread t owns embed dim t.

__global__ __launch_bounds__(128) void aggregate(
    const int* __restrict__ edges, const int* __restrict__ nidx,
    const unsigned short* __restrict__ z, const float* __restrict__ M2,
    float* __restrict__ out, int E) {
  __shared__ int s_idx1[2 * KNB * KNB];  // 200
  __shared__ int s_idx2[2 * KNB];        // 20
  __shared__ float pm[EMB];

  const int e = blockIdx.x;
  const int t = threadIdx.x;

  if (t < 2 * KNB) {
    int v = edges[e * 2 + t / KNB];
    s_idx2[t] = nidx[(size_t)v * KNB + (t % KNB)];
  }
  __syncthreads();
  for (int i = t; i < 2 * KNB * KNB; i += 128)
    s_idx1[i] = nidx[(size_t)s_idx2[i / KNB] * KNB + (i % KNB)];
  __syncthreads();

  float pooled = 0.f;
#pragma unroll
  for (int p = 0; p < 2; ++p) {
    float h = 0.f;
#pragma unroll
    for (int k = 0; k < KNB; ++k) {
      float a = 0.f;
#pragma unroll
      for (int j = 0; j < KNB; ++j) {
        int u = s_idx1[p * 100 + k * KNB + j];
        a += b2f(z[(size_t)u * EMB + t]);
      }
      h += fmaxf(a * 0.1f, 0.f);         // relu(mean_j)
    }
    pooled += h * 0.1f * 0.5f;           // mean_k, then 0.5*(p0+p1)
  }

  pm[t] = pooled;
  __syncthreads();
  if (t < 64) {
    float s0 = pm[t] * M2[t]       + pm[t + 64] * M2[t + 64];
    float s1 = pm[t] * M2[EMB + t] + pm[t + 64] * M2[EMB + t + 64];
#pragma unroll
    for (int off = 32; off > 0; off >>= 1) {
      s0 += __shfl_down(s0, off);
      s1 += __shfl_down(s1, off);
    }
    if (t == 0) { out[e * 2 + 0] = s0; out[e * 2 + 1] = s1; }
  }
}

// ---- launcher -----------------------------------------------------------

extern "C" void kernel_launch(void* const* d_in, const int* in_sizes, int n_in,
                              void* d_out, int out_size, void* d_ws, size_t ws_size,
                              hipStream_t stream) {
  const int*   edges = (const int*)d_in[0];
  const int*   nidx  = (const int*)d_in[1];
  const float* feat  = (const float*)d_in[2];
  const float* W1    = (const float*)d_in[3];
  const float* W2    = (const float*)d_in[4];
  const float* Wc    = (const float*)d_in[5];
  float* out = (float*)d_out;

  const int N = in_sizes[2] / FEAT;   // 100000
  const int E = in_sizes[0] / 2;      // 4096

  char* ws = (char*)d_ws;
  unsigned short* z   = (unsigned short*)ws;                       // N*128 bf16
  size_t zbytes = (size_t)N * EMB * sizeof(unsigned short);
  unsigned short* w1b = (unsigned short*)(ws + zbytes);            // 128*256 bf16
  float* M2 = (float*)(ws + zbytes + (size_t)EMB * FEAT * sizeof(unsigned short));

  cvt_w1 <<<(EMB * FEAT + 255) / 256, 256, 0, stream>>>(W1, w1b);
  make_m2<<<1, 256, 0, stream>>>(W2, Wc, M2);
  gemm_z <<<(N + 63) / 64, 512, 0, stream>>>(feat, w1b, z, N);
  aggregate<<<E, 128, 0, stream>>>(edges, nidx, z, M2, out, E);
}